// Round 6
// baseline (103.651 us; speedup 1.0000x reference)
//
#include <hip/hip_runtime.h>

typedef __bf16 bf16x8 __attribute__((ext_vector_type(8)));
typedef unsigned short u16;
typedef unsigned short u16x8 __attribute__((ext_vector_type(8)));
typedef float f32x4 __attribute__((ext_vector_type(4)));

#define L_SEQ 2048
#define NQT   (L_SEQ / 128)

__device__ __forceinline__ float bf2f(u16 x) {
    unsigned u = ((unsigned)x) << 16;
    return __builtin_bit_cast(float, u);
}
__device__ __forceinline__ u16 f2bf(float f) {
    unsigned u = __builtin_bit_cast(unsigned, f);
    u += 0x7FFFu + ((u >> 16) & 1u);
    return (u16)(u >> 16);
}

__device__ __forceinline__ void gload_lds16(const u16* g, u16* l) {
    __builtin_amdgcn_global_load_lds(
        (const __attribute__((address_space(1))) void*)g,
        (__attribute__((address_space(3))) void*)l, 16, 0, 0);
}

// f32 -> bf16 (RNE) for x, w_in, w_out in one launch. Sizes in 8-element units.
__global__ void cvt_all(const float* __restrict__ x, const float* __restrict__ wi,
                        const float* __restrict__ wo, u16* __restrict__ xo,
                        u16* __restrict__ wio, u16* __restrict__ woo,
                        int nx8, int nwi8, int nwo8) {
    int i = blockIdx.x * blockDim.x + threadIdx.x;
    const float* src; u16* dst;
    if (i < nx8) { src = x; dst = xo; }
    else if (i < nx8 + nwi8) { i -= nx8; src = wi; dst = wio; }
    else if (i < nx8 + nwi8 + nwo8) { i -= nx8 + nwi8; src = wo; dst = woo; }
    else return;
    const float4* p = reinterpret_cast<const float4*>(src) + (size_t)i * 2;
    const float4 a = p[0], b = p[1];
    u16x8 r;
    r[0] = f2bf(a.x); r[1] = f2bf(a.y); r[2] = f2bf(a.z); r[3] = f2bf(a.w);
    r[4] = f2bf(b.x); r[5] = f2bf(b.y); r[6] = f2bf(b.z); r[7] = f2bf(b.w);
    *(reinterpret_cast<u16x8*>(dst) + i) = r;
}

// ===== QKV GEMM: ring-4 counted-vmcnt pipeline =====
// C[m,n] = sum_k A[m,k]*W[n,k] + bias[n], bf16 in, bf16 out.
// Block 512 thr / 8 waves (2m x 4n), tile 256x256, BK=32, 4 LDS slots (128 KB).
// Phase c: vmcnt(8) [own tile-c loads landed]; s_barrier [-> ALL waves' tile-c
// landed; all waves done reading slot (c+3)&3]; stage tile c+3; ds_read tile c;
// MFMA. vmcnt never 0 in main loop (T3/T4); setprio around MFMA (T5).
__launch_bounds__(512, 2)
__global__ void gemm_qkv(const u16* __restrict__ A, const u16* __restrict__ W,
                         const float* __restrict__ bias, u16* __restrict__ C,
                         int M, int N, int K) {
    __shared__ u16 As[4][256 * 32];
    __shared__ u16 Bs[4][256 * 32];

    const int tid   = threadIdx.x;
    const int lane  = tid & 63;
    const int wid   = tid >> 6;           // 0..7
    const int wm    = wid >> 2;           // 0..1  (m half)
    const int wn    = wid & 3;            // 0..3  (n quarter)
    const int row_l = lane & 15;
    const int grp   = lane >> 4;

    // XCD-aware bijective remap (nwg % 8 == 0)
    const int nwg  = gridDim.x * gridDim.y;
    const int hw   = blockIdx.y * gridDim.x + blockIdx.x;
    const int tile = (hw & 7) * (nwg >> 3) + (hw >> 3);
    const int m0 = (tile / gridDim.x) * 256;
    const int n0 = (tile % gridDim.x) * 256;

    // staging map: thread -> (row_st = tid>>2 in [0,128), chunk c_st = tid&3);
    // issue i adds 128 rows. LDS linear: slot + i*4096 + tid*8 elements.
    // Source chunk pre-swizzled: gchunk = c_st ^ ((row>>1)&3)  (i*128 preserves bits 1-2).
    const int row_st = tid >> 2;
    const int c_st   = tid & 3;
    const int swz    = (c_st ^ ((row_st >> 1) & 3)) * 8;
    const u16* gA = A + (size_t)(m0 + row_st) * K + swz;
    const u16* gB = W + (size_t)(n0 + row_st) * K + swz;
    u16* lA = &As[0][0] + wid * 512;      // + slot*8192 + i*4096 (HW adds lane*8 el)
    u16* lB = &Bs[0][0] + wid * 512;

    f32x4 acc[8][4];
#pragma unroll
    for (int mi = 0; mi < 8; ++mi)
#pragma unroll
        for (int ni = 0; ni < 4; ++ni)
            acc[mi][ni] = (f32x4){0.f, 0.f, 0.f, 0.f};

    auto stage = [&](int slot, int kt) {
#pragma unroll
        for (int i = 0; i < 2; ++i) {
            gload_lds16(gA + (size_t)(i * 128) * K + kt * 32, lA + slot * 8192 + i * 4096);
            gload_lds16(gB + (size_t)(i * 128) * K + kt * 32, lB + slot * 8192 + i * 4096);
        }
    };

    // read chunk (uniform per lane; bits 1-2 of row come from row_l only)
    const int rchunk = (grp ^ ((row_l >> 1) & 3)) * 8;

    auto compute = [&](int slot) {
        bf16x8 a[8], b[4];
#pragma unroll
        for (int mi = 0; mi < 8; ++mi)
            a[mi] = *reinterpret_cast<const bf16x8*>(
                &As[slot][(wm * 128 + mi * 16 + row_l) * 32 + rchunk]);
#pragma unroll
        for (int ni = 0; ni < 4; ++ni)
            b[ni] = *reinterpret_cast<const bf16x8*>(
                &Bs[slot][(wn * 64 + ni * 16 + row_l) * 32 + rchunk]);
        __builtin_amdgcn_s_setprio(1);
#pragma unroll
        for (int mi = 0; mi < 8; ++mi)
#pragma unroll
            for (int ni = 0; ni < 4; ++ni)
                acc[mi][ni] = __builtin_amdgcn_mfma_f32_16x16x32_bf16(a[mi], b[ni], acc[mi][ni], 0, 0, 0);
        __builtin_amdgcn_s_setprio(0);
    };

    const int NT = K >> 5;                // 16 for K=512
    stage(0, 0); stage(1, 1); stage(2, 2);   // 12 loads in flight

    for (int c = 0; c < NT - 3; ++c) {
        asm volatile("s_waitcnt vmcnt(8)" ::: "memory");
        __builtin_amdgcn_s_barrier();
        asm volatile("" ::: "memory");
        stage((c + 3) & 3, c + 3);
        compute(c & 3);
    }
    asm volatile("s_waitcnt vmcnt(8)" ::: "memory");
    __builtin_amdgcn_s_barrier();
    asm volatile("" ::: "memory");
    compute((NT - 3) & 3);
    asm volatile("s_waitcnt vmcnt(4)" ::: "memory");
    __builtin_amdgcn_s_barrier();
    asm volatile("" ::: "memory");
    compute((NT - 2) & 3);
    asm volatile("s_waitcnt vmcnt(0)" ::: "memory");
    __builtin_amdgcn_s_barrier();
    asm volatile("" ::: "memory");
    compute((NT - 1) & 3);

#pragma unroll
    for (int ni = 0; ni < 4; ++ni) {
        const int col = n0 + wn * 64 + ni * 16 + row_l;
        const float bsf = bias[col];
#pragma unroll
        for (int mi = 0; mi < 8; ++mi) {
#pragma unroll
            for (int r = 0; r < 4; ++r) {
                const int rowm = m0 + wm * 128 + mi * 16 + grp * 4 + r;
                C[(size_t)rowm * N + col] = f2bf(acc[mi][ni][r] + bsf);
            }
        }
    }
}

// ===== out-proj GEMM: round-5 2-phase 128x128 (unchanged) =====
template <bool OUT_BF16>
__launch_bounds__(256)
__global__ void gemm_bt_bias(const u16* __restrict__ A, const u16* __restrict__ W,
                             const float* __restrict__ bias, void* __restrict__ Cv,
                             int M, int N, int K) {
    __shared__ u16 As[2][128 * 64];
    __shared__ u16 Bs[2][128 * 64];

    const int tid   = threadIdx.x;
    const int lane  = tid & 63;
    const int wid   = tid >> 6;
    const int wm    = wid >> 1;
    const int wn    = wid & 1;
    const int row_l = lane & 15;
    const int grp   = lane >> 4;

    const int nwg  = gridDim.x * gridDim.y;
    const int hw   = blockIdx.y * gridDim.x + blockIdx.x;
    const int tile = (hw & 7) * (nwg >> 3) + (hw >> 3);
    const int m0 = (tile / gridDim.x) * 128;
    const int n0 = (tile % gridDim.x) * 128;

    const int srow = tid >> 3;
    const int scol = ((tid & 7) ^ (srow & 7)) * 8;
    const u16* gA = A + (size_t)(m0 + srow) * K + scol;
    const u16* gB = W + (size_t)(n0 + srow) * K + scol;

    f32x4 acc[4][4];
#pragma unroll
    for (int mi = 0; mi < 4; ++mi)
#pragma unroll
        for (int ni = 0; ni < 4; ++ni)
            acc[mi][ni] = (f32x4){0.f, 0.f, 0.f, 0.f};

    auto stage = [&](int buf, int kt) {
#pragma unroll
        for (int i = 0; i < 4; ++i) {
            gload_lds16(gA + (size_t)(i * 32) * K + kt * 64, &As[buf][i * 2048 + wid * 512]);
            gload_lds16(gB + (size_t)(i * 32) * K + kt * 64, &Bs[buf][i * 2048 + wid * 512]);
        }
    };

    auto compute = [&](int buf) {
#pragma unroll
        for (int kk = 0; kk < 2; ++kk) {
            bf16x8 a[4], b[4];
#pragma unroll
            for (int mi = 0; mi < 4; ++mi) {
                const int row = wm * 64 + mi * 16 + row_l;
                a[mi] = *reinterpret_cast<const bf16x8*>(
                    &As[buf][row * 64 + (((kk * 4 + grp) ^ (row & 7)) * 8)]);
            }
#pragma unroll
            for (int ni = 0; ni < 4; ++ni) {
                const int row = wn * 64 + ni * 16 + row_l;
                b[ni] = *reinterpret_cast<const bf16x8*>(
                    &Bs[buf][row * 64 + (((kk * 4 + grp) ^ (row & 7)) * 8)]);
            }
#pragma unroll
            for (int mi = 0; mi < 4; ++mi)
#pragma unroll
                for (int ni = 0; ni < 4; ++ni)
                    acc[mi][ni] = __builtin_amdgcn_mfma_f32_16x16x32_bf16(a[mi], b[ni], acc[mi][ni], 0, 0, 0);
        }
    };

    const int NT = K >> 6;
    stage(0, 0);
    __syncthreads();
    for (int t = 0; t < NT - 1; ++t) {
        const int cur = t & 1;
        stage(cur ^ 1, t + 1);
        compute(cur);
        __syncthreads();
    }
    compute((NT - 1) & 1);

#pragma unroll
    for (int ni = 0; ni < 4; ++ni) {
        const int col = n0 + wn * 64 + ni * 16 + row_l;
        const float bsf = bias[col];
#pragma unroll
        for (int mi = 0; mi < 4; ++mi) {
#pragma unroll
            for (int r = 0; r < 4; ++r) {
                const int rowm = m0 + wm * 64 + mi * 16 + grp * 4 + r;
                const float v = acc[mi][ni][r] + bsf;
                if (OUT_BF16)
                    ((u16*)Cv)[(size_t)rowm * N + col] = f2bf(v);
                else
                    ((float*)Cv)[(size_t)rowm * N + col] = v;
            }
        }
    }
}

// ===== banded local attention (unchanged from round 4) =====
__launch_bounds__(512, 4)
__global__ void local_attn(const u16* __restrict__ qkv, u16* __restrict__ att) {
    __shared__ __align__(16) u16 Ks[256 * 64];
    __shared__ __align__(16) u16 Vt[64 * 256];
    __shared__ __align__(16) u16 Pl[8][512];

    const int tid   = threadIdx.x;
    const int lane  = tid & 63;
    const int wv    = tid >> 6;
    const int row_l = lane & 15;
    const int grp   = lane >> 4;
    const int qt = blockIdx.x, h = blockIdx.y, b = blockIdx.z;
    const int q0b = qt * 128;
    const int kstart = q0b - 64;
    const size_t base = (size_t)b * L_SEQ * 1536;
    const bool edge = (qt == 0) || (qt == NQT - 1);

    {
        const int r0 = tid >> 3;
        const int c  = tid & 7;
#pragma unroll
        for (int i = 0; i < 4; ++i) {
            const int row  = i * 64 + r0;
            const int keyg = min(max(kstart + row, 0), L_SEQ - 1);
            const int cg   = c ^ (row & 7);
            gload_lds16(qkv + base + (size_t)keyg * 1536 + 512 + h * 64 + cg * 8,
                        &Ks[i * 4096 + wv * 512]);
        }
    }
    {
#pragma unroll
        for (int i = 0; i < 4; ++i) {
            const int idx  = i * 512 + tid;
            const int row  = idx >> 3;
            const int c8   = idx & 7;
            const int keyg = min(max(kstart + row, 0), L_SEQ - 1);
            const u16x8 vu = *reinterpret_cast<const u16x8*>(
                qkv + base + (size_t)keyg * 1536 + 1024 + h * 64 + c8 * 8);
#pragma unroll
            for (int e = 0; e < 8; ++e) {
                const int d = c8 * 8 + e;
                Vt[d * 256 + (((row >> 3) ^ (d & 7)) * 8) + (row & 7)] = vu[e];
            }
        }
    }

    const int qrow_g = q0b + wv * 16 + row_l;
    const u16* qp = qkv + base + (size_t)qrow_g * 1536 + h * 64;
    const bf16x8 qf0 = *reinterpret_cast<const bf16x8*>(qp + grp * 8);
    const bf16x8 qf1 = *reinterpret_cast<const bf16x8*>(qp + 32 + grp * 8);

    __syncthreads();

    float m_r = -1e30f, l_r = 0.f;
    f32x4 acc[4];
#pragma unroll
    for (int ds = 0; ds < 4; ++ds) acc[ds] = (f32x4){0.f, 0.f, 0.f, 0.f};
    u16* Pw = Pl[wv];

    auto do_chunk = [&](int c, bool bandLo, bool bandHi, bool half, bool rng) {
        const int kcL = wv * 16 + 32 * c;
        const int kcG = kstart + kcL;
        const int nf = half ? 1 : 2;

        f32x4 s[2];
#pragma unroll
        for (int f = 0; f < 2; ++f) {
            if (f >= nf) break;
            const int rr = kcL + 16 * f + row_l;
            const bf16x8 ka = *reinterpret_cast<const bf16x8*>(
                &Ks[rr * 64 + ((grp ^ (rr & 7)) * 8)]);
            const bf16x8 kb = *reinterpret_cast<const bf16x8*>(
                &Ks[rr * 64 + (((grp + 4) ^ (rr & 7)) * 8)]);
            f32x4 z = (f32x4){0.f, 0.f, 0.f, 0.f};
            z = __builtin_amdgcn_mfma_f32_16x16x32_bf16(ka, qf0, z, 0, 0, 0);
            z = __builtin_amdgcn_mfma_f32_16x16x32_bf16(kb, qf1, z, 0, 0, 0);
            s[f] = z;
        }

        float p[2][4];
        float cmax = -1e30f;
#pragma unroll
        for (int f = 0; f < 2; ++f) {
            if (f >= nf) break;
#pragma unroll
            for (int r = 0; r < 4; ++r) {
                const int k = 16 * f + grp * 4 + r;
                bool ok = true;
                if (bandLo) ok = ok && (k >= row_l);
                if (bandHi) ok = ok && (k <= row_l);
                if (rng) { const int kg = kcG + k; ok = ok && (kg >= 0) && (kg < L_SEQ); }
                const float sv = ok ? s[f][r] * 0.125f : -1e30f;
                p[f][r] = sv;
                cmax = fmaxf(cmax, sv);
            }
        }
        cmax = fmaxf(cmax, __shfl_xor(cmax, 16, 64));
        cmax = fmaxf(cmax, __shfl_xor(cmax, 32, 64));
        const float mn  = fmaxf(m_r, cmax);
        const float scl = __expf(m_r - mn);
        m_r = mn;
        float lsum = 0.f;
#pragma unroll
        for (int f = 0; f < 2; ++f) {
            if (f >= nf) break;
#pragma unroll
            for (int r = 0; r < 4; ++r) {
                const float pv = (p[f][r] <= -1e29f) ? 0.f : __expf(p[f][r] - mn);
                p[f][r] = pv;
                lsum += pv;
            }
        }
        lsum += __shfl_xor(lsum, 16, 64);
        lsum += __shfl_xor(lsum, 32, 64);
        l_r = l_r * scl + lsum;

        float scl4[4];
#pragma unroll
        for (int r = 0; r < 4; ++r) scl4[r] = __shfl(scl, grp * 4 + r, 64);
#pragma unroll
        for (int ds = 0; ds < 4; ++ds)
#pragma unroll
            for (int r = 0; r < 4; ++r) acc[ds][r] *= scl4[r];

#pragma unroll
        for (int f = 0; f < 2; ++f)
#pragma unroll
            for (int r = 0; r < 4; ++r) {
                const int k = 16 * f + grp * 4 + r;
                const int slot = (k >> 3) ^ ((row_l >> 1) & 3);
                const float pv = (f < nf) ? p[f][r] : 0.f;
                Pw[row_l * 32 + slot * 8 + (k & 7)] = f2bf(pv);
            }
        const bf16x8 pa = *reinterpret_cast<const bf16x8*>(
            &Pw[row_l * 32 + ((grp ^ ((row_l >> 1) & 3)) * 8)]);

        int k0 = kcL + grp * 8;
        if (half) k0 = min(k0, 248);
#pragma unroll
        for (int ds = 0; ds < 4; ++ds) {
            const int d = ds * 16 + row_l;
            const bf16x8 vf = *reinterpret_cast<const bf16x8*>(
                &Vt[d * 256 + (((k0 >> 3) ^ (d & 7)) * 8)]);
            acc[ds] = __builtin_amdgcn_mfma_f32_16x16x32_bf16(pa, vf, acc[ds], 0, 0, 0);
        }
    };

    if (!edge) {
        do_chunk(0, true,  false, false, false);
        do_chunk(1, false, false, false, false);
        do_chunk(2, false, false, false, false);
        do_chunk(3, false, false, false, false);
        do_chunk(4, false, true,  true,  false);
    } else {
        const int kw = kstart + wv * 16;
        if (kw       > -32 && kw       < L_SEQ) do_chunk(0, true,  false, false, true);
        if (kw + 32  > -32 && kw + 32  < L_SEQ) do_chunk(1, false, false, false, true);
        if (kw + 64  > -32 && kw + 64  < L_SEQ) do_chunk(2, false, false, false, true);
        if (kw + 96  > -32 && kw + 96  < L_SEQ) do_chunk(3, false, false, false, true);
        if (kw + 128 > -32 && kw + 128 < L_SEQ) do_chunk(4, false, true,  true,  true);
    }

    const float inv = 1.f / l_r;
    float inv4[4];
#pragma unroll
    for (int r = 0; r < 4; ++r) inv4[r] = __shfl(inv, grp * 4 + r, 64);
    const int qg = q0b + wv * 16 + grp * 4;
#pragma unroll
    for (int r = 0; r < 4; ++r)
#pragma unroll
        for (int ds = 0; ds < 4; ++ds)
            att[(size_t)(b * L_SEQ + qg + r) * 512 + h * 64 + ds * 16 + row_l] =
                f2bf(acc[ds][r] * inv4[r]);
}

extern "C" void kernel_launch(void* const* d_in, const int* in_sizes, int n_in,
                              void* d_out, int out_size, void* d_ws, size_t ws_size,
                              hipStream_t stream) {
    const float* x     = (const float*)d_in[0];
    const float* w_in  = (const float*)d_in[1];
    const float* b_in  = (const float*)d_in[2];
    const float* w_out = (const float*)d_in[3];
    const float* b_out = (const float*)d_in[4];
    float* out = (float*)d_out;

    const int B = 8, L = L_SEQ;
    const int M = B * L;  // 16384

    u16* qkv   = (u16*)d_ws;                      // [M, 1536]  bf16
    u16* att   = qkv   + (size_t)M * 1536;        // [M, 512]   bf16
    u16* x_bf  = att   + (size_t)M * 512;         // [M, 512]   bf16
    u16* wi_bf = x_bf  + (size_t)M * 512;         // [1536, 512] bf16
    u16* wo_bf = wi_bf + (size_t)1536 * 512;      // [512, 512] bf16

    const int nx8  = M * 512 / 8;
    const int nwi8 = 1536 * 512 / 8;
    const int nwo8 = 512 * 512 / 8;
    const int ncvt = nx8 + nwi8 + nwo8;
    cvt_all<<<(ncvt + 255) / 256, 256, 0, stream>>>(x, w_in, w_out, x_bf, wi_bf, wo_bf,
                                                    nx8, nwi8, nwo8);

    // QKV projection: ring-4 pipelined 256x256 kernel
    gemm_qkv<<<dim3(1536 / 256, M / 256), dim3(512), 0, stream>>>(
        x_bf, wi_bf, b_in, qkv, M, 1536, 512);

    local_attn<<<dim3(NQT, 8, B), dim3(512), 0, stream>>>(qkv, att);

    gemm_bt_bias<false><<<dim3(512 / 128, M / 128), dim3(256), 0, stream>>>(
        att, wo_bf, b_out, out, M, 512, 512);
}

// Round 7
// 90.772 us; speedup vs baseline: 1.1419x; 1.1419x over previous
//
#include <hip/hip_runtime.h>

typedef __bf16 bf16x8 __attribute__((ext_vector_type(8)));
typedef unsigned short u16;
typedef unsigned short u16x8 __attribute__((ext_vector_type(8)));
typedef float f32x4 __attribute__((ext_vector_type(4)));

#define L_SEQ 2048
#define NQT   (L_SEQ / 128)

__device__ __forceinline__ float bf2f(u16 x) {
    unsigned u = ((unsigned)x) << 16;
    return __builtin_bit_cast(float, u);
}
__device__ __forceinline__ u16 f2bf(float f) {
    unsigned u = __builtin_bit_cast(unsigned, f);
    u += 0x7FFFu + ((u >> 16) & 1u);
    return (u16)(u >> 16);
}

__device__ __forceinline__ void gload_lds16(const u16* g, u16* l) {
    __builtin_amdgcn_global_load_lds(
        (const __attribute__((address_space(1))) void*)g,
        (__attribute__((address_space(3))) void*)l, 16, 0, 0);
}

// f32 -> bf16 (RNE) for x, w_in, w_out in one launch. Sizes in 8-element units.
__global__ void cvt_all(const float* __restrict__ x, const float* __restrict__ wi,
                        const float* __restrict__ wo, u16* __restrict__ xo,
                        u16* __restrict__ wio, u16* __restrict__ woo,
                        int nx8, int nwi8, int nwo8) {
    int i = blockIdx.x * blockDim.x + threadIdx.x;
    const float* src; u16* dst;
    if (i < nx8) { src = x; dst = xo; }
    else if (i < nx8 + nwi8) { i -= nx8; src = wi; dst = wio; }
    else if (i < nx8 + nwi8 + nwo8) { i -= nx8 + nwi8; src = wo; dst = woo; }
    else return;
    const float4* p = reinterpret_cast<const float4*>(src) + (size_t)i * 2;
    const float4 a = p[0], b = p[1];
    u16x8 r;
    r[0] = f2bf(a.x); r[1] = f2bf(a.y); r[2] = f2bf(a.z); r[3] = f2bf(a.w);
    r[4] = f2bf(b.x); r[5] = f2bf(b.y); r[6] = f2bf(b.z); r[7] = f2bf(b.w);
    *(reinterpret_cast<u16x8*>(dst) + i) = r;
}

// ===== GEMM: ring-3 counted-vmcnt, 128x128 tile, BK=32, 48 KB LDS =====
// C[m,n] = sum_k A[m,k]*W[n,k] + bias[n], bf16 A/W, fp32 accum.
// 256 thr / 4 waves (2m x 2n), 3 blocks/CU. Per iter t:
//   vmcnt(4) [tile t landed, tile t+1 stays in flight] ; s_barrier ;
//   stage tile t+2 into buf (t+2)%3 ; 8 ds_read + 16 MFMA on buf t%3.
// vmcnt hits 0 only at the last iteration.
template <bool OUT_BF16>
__launch_bounds__(256, 3)
__global__ void gemm_ring(const u16* __restrict__ A, const u16* __restrict__ W,
                          const float* __restrict__ bias, void* __restrict__ Cv,
                          int M, int N, int K) {
    __shared__ u16 As[3][128 * 32];
    __shared__ u16 Bs[3][128 * 32];

    const int tid   = threadIdx.x;
    const int lane  = tid & 63;
    const int wid   = tid >> 6;
    const int wm    = wid >> 1;
    const int wn    = wid & 1;
    const int row_l = lane & 15;
    const int grp   = lane >> 4;

    // XCD-aware bijective remap (nwg % 8 == 0)
    const int nwg  = gridDim.x * gridDim.y;
    const int hw   = blockIdx.y * gridDim.x + blockIdx.x;
    const int tile = (hw & 7) * (nwg >> 3) + (hw >> 3);
    const int m0 = (tile / gridDim.x) * 128;
    const int n0 = (tile % gridDim.x) * 128;

    // staging map: one issue = 64 rows x 32 cols (4 KB); thread -> row=tid>>2,
    // chunk (tid&3), source pre-swizzled: gchunk = (tid&3) ^ ((row>>1)&3).
    const int srow = tid >> 2;
    const int scol = ((tid & 3) ^ ((tid >> 3) & 3)) * 8;
    const u16* gA = A + (size_t)(m0 + srow) * K + scol;
    const u16* gB = W + (size_t)(n0 + srow) * K + scol;

    f32x4 acc[4][4];
#pragma unroll
    for (int mi = 0; mi < 4; ++mi)
#pragma unroll
        for (int ni = 0; ni < 4; ++ni)
            acc[mi][ni] = (f32x4){0.f, 0.f, 0.f, 0.f};

    auto stage = [&](int buf, int kt) {   // 4 loads/thread (2 A + 2 B)
#pragma unroll
        for (int i = 0; i < 2; ++i) {
            gload_lds16(gA + (size_t)(i * 64) * K + kt * 32, &As[buf][i * 2048 + wid * 512]);
            gload_lds16(gB + (size_t)(i * 64) * K + kt * 32, &Bs[buf][i * 2048 + wid * 512]);
        }
    };

    // read chunk: k-chunk grp, swizzled by row (only row_l bits matter: 64,16 ≡ 0 mod 8)
    const int rchunk = (grp ^ ((row_l >> 1) & 3)) * 8;

    auto compute = [&](int buf) {
        bf16x8 a[4], b[4];
#pragma unroll
        for (int mi = 0; mi < 4; ++mi)
            a[mi] = *reinterpret_cast<const bf16x8*>(
                &As[buf][(wm * 64 + mi * 16 + row_l) * 32 + rchunk]);
#pragma unroll
        for (int ni = 0; ni < 4; ++ni)
            b[ni] = *reinterpret_cast<const bf16x8*>(
                &Bs[buf][(wn * 64 + ni * 16 + row_l) * 32 + rchunk]);
        __builtin_amdgcn_s_setprio(1);
#pragma unroll
        for (int mi = 0; mi < 4; ++mi)
#pragma unroll
            for (int ni = 0; ni < 4; ++ni)
                acc[mi][ni] = __builtin_amdgcn_mfma_f32_16x16x32_bf16(a[mi], b[ni], acc[mi][ni], 0, 0, 0);
        __builtin_amdgcn_s_setprio(0);
    };

    const int NT = K >> 5;
    stage(0, 0);
    stage(1, 1);
    int cur = 0;
    for (int t = 0; t < NT; ++t) {
        if (t == NT - 1) asm volatile("s_waitcnt vmcnt(0)" ::: "memory");
        else             asm volatile("s_waitcnt vmcnt(4)" ::: "memory");
        __builtin_amdgcn_s_barrier();
        if (t + 2 < NT) {
            int st = cur + 2; if (st >= 3) st -= 3;
            stage(st, t + 2);
        }
        compute(cur);
        cur = cur + 1; if (cur >= 3) cur = 0;
    }

#pragma unroll
    for (int ni = 0; ni < 4; ++ni) {
        const int col = n0 + wn * 64 + ni * 16 + row_l;
        const float bsf = bias[col];
#pragma unroll
        for (int mi = 0; mi < 4; ++mi) {
#pragma unroll
            for (int r = 0; r < 4; ++r) {
                const int rowm = m0 + wm * 64 + mi * 16 + grp * 4 + r;
                const float v = acc[mi][ni][r] + bsf;
                if (OUT_BF16)
                    ((u16*)Cv)[(size_t)rowm * N + col] = f2bf(v);
                else
                    ((float*)Cv)[(size_t)rowm * N + col] = v;
            }
        }
    }
}

// ===== banded local attention (unchanged from round 4) =====
__launch_bounds__(512, 4)
__global__ void local_attn(const u16* __restrict__ qkv, u16* __restrict__ att) {
    __shared__ __align__(16) u16 Ks[256 * 64];
    __shared__ __align__(16) u16 Vt[64 * 256];
    __shared__ __align__(16) u16 Pl[8][512];

    const int tid   = threadIdx.x;
    const int lane  = tid & 63;
    const int wv    = tid >> 6;
    const int row_l = lane & 15;
    const int grp   = lane >> 4;
    const int qt = blockIdx.x, h = blockIdx.y, b = blockIdx.z;
    const int q0b = qt * 128;
    const int kstart = q0b - 64;
    const size_t base = (size_t)b * L_SEQ * 1536;
    const bool edge = (qt == 0) || (qt == NQT - 1);

    {
        const int r0 = tid >> 3;
        const int c  = tid & 7;
#pragma unroll
        for (int i = 0; i < 4; ++i) {
            const int row  = i * 64 + r0;
            const int keyg = min(max(kstart + row, 0), L_SEQ - 1);
            const int cg   = c ^ (row & 7);
            gload_lds16(qkv + base + (size_t)keyg * 1536 + 512 + h * 64 + cg * 8,
                        &Ks[i * 4096 + wv * 512]);
        }
    }
    {
#pragma unroll
        for (int i = 0; i < 4; ++i) {
            const int idx  = i * 512 + tid;
            const int row  = idx >> 3;
            const int c8   = idx & 7;
            const int keyg = min(max(kstart + row, 0), L_SEQ - 1);
            const u16x8 vu = *reinterpret_cast<const u16x8*>(
                qkv + base + (size_t)keyg * 1536 + 1024 + h * 64 + c8 * 8);
#pragma unroll
            for (int e = 0; e < 8; ++e) {
                const int d = c8 * 8 + e;
                Vt[d * 256 + (((row >> 3) ^ (d & 7)) * 8) + (row & 7)] = vu[e];
            }
        }
    }

    const int qrow_g = q0b + wv * 16 + row_l;
    const u16* qp = qkv + base + (size_t)qrow_g * 1536 + h * 64;
    const bf16x8 qf0 = *reinterpret_cast<const bf16x8*>(qp + grp * 8);
    const bf16x8 qf1 = *reinterpret_cast<const bf16x8*>(qp + 32 + grp * 8);

    __syncthreads();

    float m_r = -1e30f, l_r = 0.f;
    f32x4 acc[4];
#pragma unroll
    for (int ds = 0; ds < 4; ++ds) acc[ds] = (f32x4){0.f, 0.f, 0.f, 0.f};
    u16* Pw = Pl[wv];

    auto do_chunk = [&](int c, bool bandLo, bool bandHi, bool half, bool rng) {
        const int kcL = wv * 16 + 32 * c;
        const int kcG = kstart + kcL;
        const int nf = half ? 1 : 2;

        f32x4 s[2];
#pragma unroll
        for (int f = 0; f < 2; ++f) {
            if (f >= nf) break;
            const int rr = kcL + 16 * f + row_l;
            const bf16x8 ka = *reinterpret_cast<const bf16x8*>(
                &Ks[rr * 64 + ((grp ^ (rr & 7)) * 8)]);
            const bf16x8 kb = *reinterpret_cast<const bf16x8*>(
                &Ks[rr * 64 + (((grp + 4) ^ (rr & 7)) * 8)]);
            f32x4 z = (f32x4){0.f, 0.f, 0.f, 0.f};
            z = __builtin_amdgcn_mfma_f32_16x16x32_bf16(ka, qf0, z, 0, 0, 0);
            z = __builtin_amdgcn_mfma_f32_16x16x32_bf16(kb, qf1, z, 0, 0, 0);
            s[f] = z;
        }

        float p[2][4];
        float cmax = -1e30f;
#pragma unroll
        for (int f = 0; f < 2; ++f) {
            if (f >= nf) break;
#pragma unroll
            for (int r = 0; r < 4; ++r) {
                const int k = 16 * f + grp * 4 + r;
                bool ok = true;
                if (bandLo) ok = ok && (k >= row_l);
                if (bandHi) ok = ok && (k <= row_l);
                if (rng) { const int kg = kcG + k; ok = ok && (kg >= 0) && (kg < L_SEQ); }
                const float sv = ok ? s[f][r] * 0.125f : -1e30f;
                p[f][r] = sv;
                cmax = fmaxf(cmax, sv);
            }
        }
        cmax = fmaxf(cmax, __shfl_xor(cmax, 16, 64));
        cmax = fmaxf(cmax, __shfl_xor(cmax, 32, 64));
        const float mn  = fmaxf(m_r, cmax);
        const float scl = __expf(m_r - mn);
        m_r = mn;
        float lsum = 0.f;
#pragma unroll
        for (int f = 0; f < 2; ++f) {
            if (f >= nf) break;
#pragma unroll
            for (int r = 0; r < 4; ++r) {
                const float pv = (p[f][r] <= -1e29f) ? 0.f : __expf(p[f][r] - mn);
                p[f][r] = pv;
                lsum += pv;
            }
        }
        lsum += __shfl_xor(lsum, 16, 64);
        lsum += __shfl_xor(lsum, 32, 64);
        l_r = l_r * scl + lsum;

        float scl4[4];
#pragma unroll
        for (int r = 0; r < 4; ++r) scl4[r] = __shfl(scl, grp * 4 + r, 64);
#pragma unroll
        for (int ds = 0; ds < 4; ++ds)
#pragma unroll
            for (int r = 0; r < 4; ++r) acc[ds][r] *= scl4[r];

#pragma unroll
        for (int f = 0; f < 2; ++f)
#pragma unroll
            for (int r = 0; r < 4; ++r) {
                const int k = 16 * f + grp * 4 + r;
                const int slot = (k >> 3) ^ ((row_l >> 1) & 3);
                const float pv = (f < nf) ? p[f][r] : 0.f;
                Pw[row_l * 32 + slot * 8 + (k & 7)] = f2bf(pv);
            }
        const bf16x8 pa = *reinterpret_cast<const bf16x8*>(
            &Pw[row_l * 32 + ((grp ^ ((row_l >> 1) & 3)) * 8)]);

        int k0 = kcL + grp * 8;
        if (half) k0 = min(k0, 248);
#pragma unroll
        for (int ds = 0; ds < 4; ++ds) {
            const int d = ds * 16 + row_l;
            const bf16x8 vf = *reinterpret_cast<const bf16x8*>(
                &Vt[d * 256 + (((k0 >> 3) ^ (d & 7)) * 8)]);
            acc[ds] = __builtin_amdgcn_mfma_f32_16x16x32_bf16(pa, vf, acc[ds], 0, 0, 0);
        }
    };

    if (!edge) {
        do_chunk(0, true,  false, false, false);
        do_chunk(1, false, false, false, false);
        do_chunk(2, false, false, false, false);
        do_chunk(3, false, false, false, false);
        do_chunk(4, false, true,  true,  false);
    } else {
        const int kw = kstart + wv * 16;
        if (kw       > -32 && kw       < L_SEQ) do_chunk(0, true,  false, false, true);
        if (kw + 32  > -32 && kw + 32  < L_SEQ) do_chunk(1, false, false, false, true);
        if (kw + 64  > -32 && kw + 64  < L_SEQ) do_chunk(2, false, false, false, true);
        if (kw + 96  > -32 && kw + 96  < L_SEQ) do_chunk(3, false, false, false, true);
        if (kw + 128 > -32 && kw + 128 < L_SEQ) do_chunk(4, false, true,  true,  true);
    }

    const float inv = 1.f / l_r;
    float inv4[4];
#pragma unroll
    for (int r = 0; r < 4; ++r) inv4[r] = __shfl(inv, grp * 4 + r, 64);
    const int qg = q0b + wv * 16 + grp * 4;
#pragma unroll
    for (int r = 0; r < 4; ++r)
#pragma unroll
        for (int ds = 0; ds < 4; ++ds)
            att[(size_t)(b * L_SEQ + qg + r) * 512 + h * 64 + ds * 16 + row_l] =
                f2bf(acc[ds][r] * inv4[r]);
}

extern "C" void kernel_launch(void* const* d_in, const int* in_sizes, int n_in,
                              void* d_out, int out_size, void* d_ws, size_t ws_size,
                              hipStream_t stream) {
    const float* x     = (const float*)d_in[0];
    const float* w_in  = (const float*)d_in[1];
    const float* b_in  = (const float*)d_in[2];
    const float* w_out = (const float*)d_in[3];
    const float* b_out = (const float*)d_in[4];
    float* out = (float*)d_out;

    const int B = 8, L = L_SEQ;
    const int M = B * L;  // 16384

    u16* qkv   = (u16*)d_ws;                      // [M, 1536]  bf16
    u16* att   = qkv   + (size_t)M * 1536;        // [M, 512]   bf16
    u16* x_bf  = att   + (size_t)M * 512;         // [M, 512]   bf16
    u16* wi_bf = x_bf  + (size_t)M * 512;         // [1536, 512] bf16
    u16* wo_bf = wi_bf + (size_t)1536 * 512;      // [512, 512] bf16

    const int nx8  = M * 512 / 8;
    const int nwi8 = 1536 * 512 / 8;
    const int nwo8 = 512 * 512 / 8;
    const int ncvt = nx8 + nwi8 + nwo8;
    cvt_all<<<(ncvt + 255) / 256, 256, 0, stream>>>(x, w_in, w_out, x_bf, wi_bf, wo_bf,
                                                    nx8, nwi8, nwo8);

    gemm_ring<true><<<dim3(1536 / 128, M / 128), dim3(256), 0, stream>>>(
        x_bf, wi_bf, b_in, qkv, M, 1536, 512);

    local_attn<<<dim3(NQT, 8, B), dim3(512), 0, stream>>>(qkv, att);

    gemm_ring<false><<<dim3(512 / 128, M / 128), dim3(256), 0, stream>>>(
        att, wo_bf, b_out, out, M, 512, 512);
}

// Round 8
// 88.398 us; speedup vs baseline: 1.1726x; 1.0269x over previous
//
#include <hip/hip_runtime.h>

typedef __bf16 bf16x8 __attribute__((ext_vector_type(8)));
typedef unsigned short u16;
typedef unsigned short u16x8 __attribute__((ext_vector_type(8)));
typedef float f32x4 __attribute__((ext_vector_type(4)));

#define L_SEQ 2048
#define NQT   (L_SEQ / 128)

__device__ __forceinline__ float bf2f(u16 x) {
    unsigned u = ((unsigned)x) << 16;
    return __builtin_bit_cast(float, u);
}
__device__ __forceinline__ u16 f2bf(float f) {
    unsigned u = __builtin_bit_cast(unsigned, f);
    u += 0x7FFFu + ((u >> 16) & 1u);
    return (u16)(u >> 16);
}

__device__ __forceinline__ void gload_lds16(const u16* g, u16* l) {
    __builtin_amdgcn_global_load_lds(
        (const __attribute__((address_space(1))) void*)g,
        (__attribute__((address_space(3))) void*)l, 16, 0, 0);
}

// f32 -> bf16 (RNE) for x, w_in, w_out in one launch. Sizes in 8-element units.
__global__ void cvt_all(const float* __restrict__ x, const float* __restrict__ wi,
                        const float* __restrict__ wo, u16* __restrict__ xo,
                        u16* __restrict__ wio, u16* __restrict__ woo,
                        int nx8, int nwi8, int nwo8) {
    int i = blockIdx.x * blockDim.x + threadIdx.x;
    const float* src; u16* dst;
    if (i < nx8) { src = x; dst = xo; }
    else if (i < nx8 + nwi8) { i -= nx8; src = wi; dst = wio; }
    else if (i < nx8 + nwi8 + nwo8) { i -= nx8 + nwi8; src = wo; dst = woo; }
    else return;
    const float4* p = reinterpret_cast<const float4*>(src) + (size_t)i * 2;
    const float4 a = p[0], b = p[1];
    u16x8 r;
    r[0] = f2bf(a.x); r[1] = f2bf(a.y); r[2] = f2bf(a.z); r[3] = f2bf(a.w);
    r[4] = f2bf(b.x); r[5] = f2bf(b.y); r[6] = f2bf(b.z); r[7] = f2bf(b.w);
    *(reinterpret_cast<u16x8*>(dst) + i) = r;
}

// ===== QKV GEMM: 256x128 tile, BK=32, ring-3 (72 KB), 8 waves =====
// C[m,n] = sum_k A[m,k]*W[n,k] + bias[n], bf16 in/out, fp32 accum.
// 512 thr = 8 waves (4m x 2n), wave tile 64x64 (acc 4x4 f32x4).
// Per K-tile: 8 ds_read_b128 + 3 gload_lds issues + 16 MFMA between barriers;
// vmcnt(3) keeps kt+2's loads in flight (drain only at the tail).
__launch_bounds__(512, 4)
__global__ void gemm_qkv(const u16* __restrict__ A, const u16* __restrict__ W,
                         const float* __restrict__ bias, u16* __restrict__ C,
                         int M, int N, int K) {
    __shared__ u16 As[3][256 * 32];
    __shared__ u16 Bs[3][128 * 32];

    const int tid   = threadIdx.x;
    const int lane  = tid & 63;
    const int wid   = tid >> 6;           // 0..7
    const int wm    = wid >> 1;           // 0..3 (m quarter)
    const int wn    = wid & 1;            // 0..1 (n half)
    const int row_l = lane & 15;
    const int grp   = lane >> 4;

    // XCD-aware bijective remap (nwg % 8 == 0)
    const int nwg  = gridDim.x * gridDim.y;
    const int hw   = blockIdx.y * gridDim.x + blockIdx.x;
    const int tile = (hw & 7) * (nwg >> 3) + (hw >> 3);
    const int m0 = (tile / gridDim.x) * 256;
    const int n0 = (tile % gridDim.x) * 128;

    // staging map: issue = 128 rows x 32 cols (8 KB); thread -> row = tid>>2,
    // chunk (tid&3); source pre-swizzled: gchunk = (tid&3) ^ ((row>>1)&3).
    const int srow = tid >> 2;                       // 0..127
    const int scol = ((tid & 3) ^ ((tid >> 3) & 3)) * 8;
    const u16* gA = A + (size_t)(m0 + srow) * K + scol;
    const u16* gB = W + (size_t)(n0 + srow) * K + scol;

    f32x4 acc[4][4];
#pragma unroll
    for (int mi = 0; mi < 4; ++mi)
#pragma unroll
        for (int ni = 0; ni < 4; ++ni)
            acc[mi][ni] = (f32x4){0.f, 0.f, 0.f, 0.f};

    auto stage = [&](int buf, int kt) {   // 3 issues/thread: A rows 0-127,128-255; B rows 0-127
        gload_lds16(gA + (size_t)kt * 32,                   &As[buf][0]    + wid * 512);
        gload_lds16(gA + (size_t)128 * K + (size_t)kt * 32, &As[buf][4096] + wid * 512);
        gload_lds16(gB + (size_t)kt * 32,                   &Bs[buf][0]    + wid * 512);
    };

    const int rchunk = (grp ^ ((row_l >> 1) & 3)) * 8;

    const int NT = K >> 5;                // 16
    stage(0, 0);
    stage(1, 1);
    asm volatile("s_waitcnt vmcnt(3)" ::: "memory");
    __builtin_amdgcn_s_barrier();

    int buf = 0;
    for (int kt = 0; kt < NT; ++kt) {
        // ds_read fragments of tile kt (valid: retired + double-barriered last iter)
        bf16x8 a[4], b[4];
#pragma unroll
        for (int mi = 0; mi < 4; ++mi)
            a[mi] = *reinterpret_cast<const bf16x8*>(
                &As[buf][(wm * 64 + mi * 16 + row_l) * 32 + rchunk]);
#pragma unroll
        for (int ni = 0; ni < 4; ++ni)
            b[ni] = *reinterpret_cast<const bf16x8*>(
                &Bs[buf][(wn * 64 + ni * 16 + row_l) * 32 + rchunk]);

        // prefetch tile kt+2 into the buffer last read at kt-1 (barrier-separated)
        if (kt + 2 < NT) {
            int st = buf + 2; if (st >= 3) st -= 3;
            stage(st, kt + 2);
        }
        // retire kt+1's loads (kt+2 stays in flight); drain only at the tail
        if (kt < NT - 2)       asm volatile("s_waitcnt vmcnt(3)" ::: "memory");
        else if (kt == NT - 2) asm volatile("s_waitcnt vmcnt(0)" ::: "memory");
        __builtin_amdgcn_s_barrier();
        asm volatile("s_waitcnt lgkmcnt(0)" ::: "memory");
        __builtin_amdgcn_sched_barrier(0);
        __builtin_amdgcn_s_setprio(1);
#pragma unroll
        for (int mi = 0; mi < 4; ++mi)
#pragma unroll
            for (int ni = 0; ni < 4; ++ni)
                acc[mi][ni] = __builtin_amdgcn_mfma_f32_16x16x32_bf16(a[mi], b[ni], acc[mi][ni], 0, 0, 0);
        __builtin_amdgcn_s_setprio(0);
        __builtin_amdgcn_s_barrier();
        buf = buf + 1; if (buf >= 3) buf = 0;
    }

#pragma unroll
    for (int ni = 0; ni < 4; ++ni) {
        const int col = n0 + wn * 64 + ni * 16 + row_l;
        const float bsf = bias[col];
#pragma unroll
        for (int mi = 0; mi < 4; ++mi) {
#pragma unroll
            for (int r = 0; r < 4; ++r) {
                const int rowm = m0 + wm * 64 + mi * 16 + grp * 4 + r;
                C[(size_t)rowm * N + col] = f2bf(acc[mi][ni][r] + bsf);
            }
        }
    }
}

// ===== out-proj GEMM: ring-3 128x128 (round-7, unchanged) =====
template <bool OUT_BF16>
__launch_bounds__(256, 3)
__global__ void gemm_ring(const u16* __restrict__ A, const u16* __restrict__ W,
                          const float* __restrict__ bias, void* __restrict__ Cv,
                          int M, int N, int K) {
    __shared__ u16 As[3][128 * 32];
    __shared__ u16 Bs[3][128 * 32];

    const int tid   = threadIdx.x;
    const int lane  = tid & 63;
    const int wid   = tid >> 6;
    const int wm    = wid >> 1;
    const int wn    = wid & 1;
    const int row_l = lane & 15;
    const int grp   = lane >> 4;

    const int nwg  = gridDim.x * gridDim.y;
    const int hw   = blockIdx.y * gridDim.x + blockIdx.x;
    const int tile = (hw & 7) * (nwg >> 3) + (hw >> 3);
    const int m0 = (tile / gridDim.x) * 128;
    const int n0 = (tile % gridDim.x) * 128;

    const int srow = tid >> 2;
    const int scol = ((tid & 3) ^ ((tid >> 3) & 3)) * 8;
    const u16* gA = A + (size_t)(m0 + srow) * K + scol;
    const u16* gB = W + (size_t)(n0 + srow) * K + scol;

    f32x4 acc[4][4];
#pragma unroll
    for (int mi = 0; mi < 4; ++mi)
#pragma unroll
        for (int ni = 0; ni < 4; ++ni)
            acc[mi][ni] = (f32x4){0.f, 0.f, 0.f, 0.f};

    auto stage = [&](int buf, int kt) {
#pragma unroll
        for (int i = 0; i < 2; ++i) {
            gload_lds16(gA + (size_t)(i * 64) * K + kt * 32, &As[buf][i * 2048 + wid * 512]);
            gload_lds16(gB + (size_t)(i * 64) * K + kt * 32, &Bs[buf][i * 2048 + wid * 512]);
        }
    };

    const int rchunk = (grp ^ ((row_l >> 1) & 3)) * 8;

    auto compute = [&](int buf) {
        bf16x8 a[4], b[4];
#pragma unroll
        for (int mi = 0; mi < 4; ++mi)
            a[mi] = *reinterpret_cast<const bf16x8*>(
                &As[buf][(wm * 64 + mi * 16 + row_l) * 32 + rchunk]);
#pragma unroll
        for (int ni = 0; ni < 4; ++ni)
            b[ni] = *reinterpret_cast<const bf16x8*>(
                &Bs[buf][(wn * 64 + ni * 16 + row_l) * 32 + rchunk]);
        __builtin_amdgcn_s_setprio(1);
#pragma unroll
        for (int mi = 0; mi < 4; ++mi)
#pragma unroll
            for (int ni = 0; ni < 4; ++ni)
                acc[mi][ni] = __builtin_amdgcn_mfma_f32_16x16x32_bf16(a[mi], b[ni], acc[mi][ni], 0, 0, 0);
        __builtin_amdgcn_s_setprio(0);
    };

    const int NT = K >> 5;
    stage(0, 0);
    stage(1, 1);
    int cur = 0;
    for (int t = 0; t < NT; ++t) {
        if (t == NT - 1) asm volatile("s_waitcnt vmcnt(0)" ::: "memory");
        else             asm volatile("s_waitcnt vmcnt(4)" ::: "memory");
        __builtin_amdgcn_s_barrier();
        if (t + 2 < NT) {
            int st = cur + 2; if (st >= 3) st -= 3;
            stage(st, t + 2);
        }
        compute(cur);
        cur = cur + 1; if (cur >= 3) cur = 0;
    }

#pragma unroll
    for (int ni = 0; ni < 4; ++ni) {
        const int col = n0 + wn * 64 + ni * 16 + row_l;
        const float bsf = bias[col];
#pragma unroll
        for (int mi = 0; mi < 4; ++mi) {
#pragma unroll
            for (int r = 0; r < 4; ++r) {
                const int rowm = m0 + wm * 64 + mi * 16 + grp * 4 + r;
                const float v = acc[mi][ni][r] + bsf;
                if (OUT_BF16)
                    ((u16*)Cv)[(size_t)rowm * N + col] = f2bf(v);
                else
                    ((float*)Cv)[(size_t)rowm * N + col] = v;
            }
        }
    }
}

// ===== banded local attention (unchanged from round 4) =====
__launch_bounds__(512, 4)
__global__ void local_attn(const u16* __restrict__ qkv, u16* __restrict__ att) {
    __shared__ __align__(16) u16 Ks[256 * 64];
    __shared__ __align__(16) u16 Vt[64 * 256];
    __shared__ __align__(16) u16 Pl[8][512];

    const int tid   = threadIdx.x;
    const int lane  = tid & 63;
    const int wv    = tid >> 6;
    const int row_l = lane & 15;
    const int grp   = lane >> 4;
    const int qt = blockIdx.x, h = blockIdx.y, b = blockIdx.z;
    const int q0b = qt * 128;
    const int kstart = q0b - 64;
    const size_t base = (size_t)b * L_SEQ * 1536;
    const bool edge = (qt == 0) || (qt == NQT - 1);

    {
        const int r0 = tid >> 3;
        const int c  = tid & 7;
#pragma unroll
        for (int i = 0; i < 4; ++i) {
            const int row  = i * 64 + r0;
            const int keyg = min(max(kstart + row, 0), L_SEQ - 1);
            const int cg   = c ^ (row & 7);
            gload_lds16(qkv + base + (size_t)keyg * 1536 + 512 + h * 64 + cg * 8,
                        &Ks[i * 4096 + wv * 512]);
        }
    }
    {
#pragma unroll
        for (int i = 0; i < 4; ++i) {
            const int idx  = i * 512 + tid;
            const int row  = idx >> 3;
            const int c8   = idx & 7;
            const int keyg = min(max(kstart + row, 0), L_SEQ - 1);
            const u16x8 vu = *reinterpret_cast<const u16x8*>(
                qkv + base + (size_t)keyg * 1536 + 1024 + h * 64 + c8 * 8);
#pragma unroll
            for (int e = 0; e < 8; ++e) {
                const int d = c8 * 8 + e;
                Vt[d * 256 + (((row >> 3) ^ (d & 7)) * 8) + (row & 7)] = vu[e];
            }
        }
    }

    const int qrow_g = q0b + wv * 16 + row_l;
    const u16* qp = qkv + base + (size_t)qrow_g * 1536 + h * 64;
    const bf16x8 qf0 = *reinterpret_cast<const bf16x8*>(qp + grp * 8);
    const bf16x8 qf1 = *reinterpret_cast<const bf16x8*>(qp + 32 + grp * 8);

    __syncthreads();

    float m_r = -1e30f, l_r = 0.f;
    f32x4 acc[4];
#pragma unroll
    for (int ds = 0; ds < 4; ++ds) acc[ds] = (f32x4){0.f, 0.f, 0.f, 0.f};
    u16* Pw = Pl[wv];

    auto do_chunk = [&](int c, bool bandLo, bool bandHi, bool half, bool rng) {
        const int kcL = wv * 16 + 32 * c;
        const int kcG = kstart + kcL;
        const int nf = half ? 1 : 2;

        f32x4 s[2];
#pragma unroll
        for (int f = 0; f < 2; ++f) {
            if (f >= nf) break;
            const int rr = kcL + 16 * f + row_l;
            const bf16x8 ka = *reinterpret_cast<const bf16x8*>(
                &Ks[rr * 64 + ((grp ^ (rr & 7)) * 8)]);
            const bf16x8 kb = *reinterpret_cast<const bf16x8*>(
                &Ks[rr * 64 + (((grp + 4) ^ (rr & 7)) * 8)]);
            f32x4 z = (f32x4){0.f, 0.f, 0.f, 0.f};
            z = __builtin_amdgcn_mfma_f32_16x16x32_bf16(ka, qf0, z, 0, 0, 0);
            z = __builtin_amdgcn_mfma_f32_16x16x32_bf16(kb, qf1, z, 0, 0, 0);
            s[f] = z;
        }

        float p[2][4];
        float cmax = -1e30f;
#pragma unroll
        for (int f = 0; f < 2; ++f) {
            if (f >= nf) break;
#pragma unroll
            for (int r = 0; r < 4; ++r) {
                const int k = 16 * f + grp * 4 + r;
                bool ok = true;
                if (bandLo) ok = ok && (k >= row_l);
                if (bandHi) ok = ok && (k <= row_l);
                if (rng) { const int kg = kcG + k; ok = ok && (kg >= 0) && (kg < L_SEQ); }
                const float sv = ok ? s[f][r] * 0.125f : -1e30f;
                p[f][r] = sv;
                cmax = fmaxf(cmax, sv);
            }
        }
        cmax = fmaxf(cmax, __shfl_xor(cmax, 16, 64));
        cmax = fmaxf(cmax, __shfl_xor(cmax, 32, 64));
        const float mn  = fmaxf(m_r, cmax);
        const float scl = __expf(m_r - mn);
        m_r = mn;
        float lsum = 0.f;
#pragma unroll
        for (int f = 0; f < 2; ++f) {
            if (f >= nf) break;
#pragma unroll
            for (int r = 0; r < 4; ++r) {
                const float pv = (p[f][r] <= -1e29f) ? 0.f : __expf(p[f][r] - mn);
                p[f][r] = pv;
                lsum += pv;
            }
        }
        lsum += __shfl_xor(lsum, 16, 64);
        lsum += __shfl_xor(lsum, 32, 64);
        l_r = l_r * scl + lsum;

        float scl4[4];
#pragma unroll
        for (int r = 0; r < 4; ++r) scl4[r] = __shfl(scl, grp * 4 + r, 64);
#pragma unroll
        for (int ds = 0; ds < 4; ++ds)
#pragma unroll
            for (int r = 0; r < 4; ++r) acc[ds][r] *= scl4[r];

#pragma unroll
        for (int f = 0; f < 2; ++f)
#pragma unroll
            for (int r = 0; r < 4; ++r) {
                const int k = 16 * f + grp * 4 + r;
                const int slot = (k >> 3) ^ ((row_l >> 1) & 3);
                const float pv = (f < nf) ? p[f][r] : 0.f;
                Pw[row_l * 32 + slot * 8 + (k & 7)] = f2bf(pv);
            }
        const bf16x8 pa = *reinterpret_cast<const bf16x8*>(
            &Pw[row_l * 32 + ((grp ^ ((row_l >> 1) & 3)) * 8)]);

        int k0 = kcL + grp * 8;
        if (half) k0 = min(k0, 248);
#pragma unroll
        for (int ds = 0; ds < 4; ++ds) {
            const int d = ds * 16 + row_l;
            const bf16x8 vf = *reinterpret_cast<const bf16x8*>(
                &Vt[d * 256 + (((k0 >> 3) ^ (d & 7)) * 8)]);
            acc[ds] = __builtin_amdgcn_mfma_f32_16x16x32_bf16(pa, vf, acc[ds], 0, 0, 0);
        }
    };

    if (!edge) {
        do_chunk(0, true,  false, false, false);
        do_chunk(1, false, false, false, false);
        do_chunk(2, false, false, false, false);
        do_chunk(3, false, false, false, false);
        do_chunk(4, false, true,  true,  false);
    } else {
        const int kw = kstart + wv * 16;
        if (kw       > -32 && kw       < L_SEQ) do_chunk(0, true,  false, false, true);
        if (kw + 32  > -32 && kw + 32  < L_SEQ) do_chunk(1, false, false, false, true);
        if (kw + 64  > -32 && kw + 64  < L_SEQ) do_chunk(2, false, false, false, true);
        if (kw + 96  > -32 && kw + 96  < L_SEQ) do_chunk(3, false, false, false, true);
        if (kw + 128 > -32 && kw + 128 < L_SEQ) do_chunk(4, false, true,  true,  true);
    }

    const float inv = 1.f / l_r;
    float inv4[4];
#pragma unroll
    for (int r = 0; r < 4; ++r) inv4[r] = __shfl(inv, grp * 4 + r, 64);
    const int qg = q0b + wv * 16 + grp * 4;
#pragma unroll
    for (int r = 0; r < 4; ++r)
#pragma unroll
        for (int ds = 0; ds < 4; ++ds)
            att[(size_t)(b * L_SEQ + qg + r) * 512 + h * 64 + ds * 16 + row_l] =
                f2bf(acc[ds][r] * inv4[r]);
}

extern "C" void kernel_launch(void* const* d_in, const int* in_sizes, int n_in,
                              void* d_out, int out_size, void* d_ws, size_t ws_size,
                              hipStream_t stream) {
    const float* x     = (const float*)d_in[0];
    const float* w_in  = (const float*)d_in[1];
    const float* b_in  = (const float*)d_in[2];
    const float* w_out = (const float*)d_in[3];
    const float* b_out = (const float*)d_in[4];
    float* out = (float*)d_out;

    const int B = 8, L = L_SEQ;
    const int M = B * L;  // 16384

    u16* qkv   = (u16*)d_ws;                      // [M, 1536]  bf16
    u16* att   = qkv   + (size_t)M * 1536;        // [M, 512]   bf16
    u16* x_bf  = att   + (size_t)M * 512;         // [M, 512]   bf16
    u16* wi_bf = x_bf  + (size_t)M * 512;         // [1536, 512] bf16
    u16* wo_bf = wi_bf + (size_t)1536 * 512;      // [512, 512] bf16

    const int nx8  = M * 512 / 8;
    const int nwi8 = 1536 * 512 / 8;
    const int nwo8 = 512 * 512 / 8;
    const int ncvt = nx8 + nwi8 + nwo8;
    cvt_all<<<(ncvt + 255) / 256, 256, 0, stream>>>(x, w_in, w_out, x_bf, wi_bf, wo_bf,
                                                    nx8, nwi8, nwo8);

    // QKV projection: 256x128 tile, 8 waves, ring-3 counted-vmcnt
    gemm_qkv<<<dim3(1536 / 128, M / 256), dim3(512), 0, stream>>>(
        x_bf, wi_bf, b_in, qkv, M, 1536, 512);

    local_attn<<<dim3(NQT, 8, B), dim3(512), 0, stream>>>(qkv, att);

    gemm_ring<false><<<dim3(512 / 128, M / 128), dim3(256), 0, stream>>>(
        att, wo_bf, b_out, out, M, 512, 512);
}

// Round 9
// 86.897 us; speedup vs baseline: 1.1928x; 1.0173x over previous
//
#include <hip/hip_runtime.h>

typedef __bf16 bf16x8 __attribute__((ext_vector_type(8)));
typedef unsigned short u16;
typedef unsigned short u16x8 __attribute__((ext_vector_type(8)));
typedef float f32x4 __attribute__((ext_vector_type(4)));

#define L_SEQ 2048
#define NQT   (L_SEQ / 128)

__device__ __forceinline__ float bf2f(u16 x) {
    unsigned u = ((unsigned)x) << 16;
    return __builtin_bit_cast(float, u);
}
__device__ __forceinline__ u16 f2bf(float f) {
    unsigned u = __builtin_bit_cast(unsigned, f);
    u += 0x7FFFu + ((u >> 16) & 1u);
    return (u16)(u >> 16);
}

__device__ __forceinline__ void gload_lds16(const u16* g, u16* l) {
    __builtin_amdgcn_global_load_lds(
        (const __attribute__((address_space(1))) void*)g,
        (__attribute__((address_space(3))) void*)l, 16, 0, 0);
}

// f32 -> bf16 (RNE) for x, w_in, w_out in one launch. Sizes in 8-element units.
__global__ void cvt_all(const float* __restrict__ x, const float* __restrict__ wi,
                        const float* __restrict__ wo, u16* __restrict__ xo,
                        u16* __restrict__ wio, u16* __restrict__ woo,
                        int nx8, int nwi8, int nwo8) {
    int i = blockIdx.x * blockDim.x + threadIdx.x;
    const float* src; u16* dst;
    if (i < nx8) { src = x; dst = xo; }
    else if (i < nx8 + nwi8) { i -= nx8; src = wi; dst = wio; }
    else if (i < nx8 + nwi8 + nwo8) { i -= nx8 + nwi8; src = wo; dst = woo; }
    else return;
    const float4* p = reinterpret_cast<const float4*>(src) + (size_t)i * 2;
    const float4 a = p[0], b = p[1];
    u16x8 r;
    r[0] = f2bf(a.x); r[1] = f2bf(a.y); r[2] = f2bf(a.z); r[3] = f2bf(a.w);
    r[4] = f2bf(b.x); r[5] = f2bf(b.y); r[6] = f2bf(b.z); r[7] = f2bf(b.w);
    *(reinterpret_cast<u16x8*>(dst) + i) = r;
}

// ===== QKV GEMM: 256x128 tile, BK=32, ring-3 (72 KB), 8 waves (round-8, unchanged) =====
__launch_bounds__(512, 4)
__global__ void gemm_qkv(const u16* __restrict__ A, const u16* __restrict__ W,
                         const float* __restrict__ bias, u16* __restrict__ C,
                         int M, int N, int K) {
    __shared__ u16 As[3][256 * 32];
    __shared__ u16 Bs[3][128 * 32];

    const int tid   = threadIdx.x;
    const int lane  = tid & 63;
    const int wid   = tid >> 6;           // 0..7
    const int wm    = wid >> 1;           // 0..3 (m quarter)
    const int wn    = wid & 1;            // 0..1 (n half)
    const int row_l = lane & 15;
    const int grp   = lane >> 4;

    const int nwg  = gridDim.x * gridDim.y;
    const int hw   = blockIdx.y * gridDim.x + blockIdx.x;
    const int tile = (hw & 7) * (nwg >> 3) + (hw >> 3);
    const int m0 = (tile / gridDim.x) * 256;
    const int n0 = (tile % gridDim.x) * 128;

    const int srow = tid >> 2;                       // 0..127
    const int scol = ((tid & 3) ^ ((tid >> 3) & 3)) * 8;
    const u16* gA = A + (size_t)(m0 + srow) * K + scol;
    const u16* gB = W + (size_t)(n0 + srow) * K + scol;

    f32x4 acc[4][4];
#pragma unroll
    for (int mi = 0; mi < 4; ++mi)
#pragma unroll
        for (int ni = 0; ni < 4; ++ni)
            acc[mi][ni] = (f32x4){0.f, 0.f, 0.f, 0.f};

    auto stage = [&](int buf, int kt) {
        gload_lds16(gA + (size_t)kt * 32,                   &As[buf][0]    + wid * 512);
        gload_lds16(gA + (size_t)128 * K + (size_t)kt * 32, &As[buf][4096] + wid * 512);
        gload_lds16(gB + (size_t)kt * 32,                   &Bs[buf][0]    + wid * 512);
    };

    const int rchunk = (grp ^ ((row_l >> 1) & 3)) * 8;

    const int NT = K >> 5;                // 16
    stage(0, 0);
    stage(1, 1);
    asm volatile("s_waitcnt vmcnt(3)" ::: "memory");
    __builtin_amdgcn_s_barrier();

    int buf = 0;
    for (int kt = 0; kt < NT; ++kt) {
        bf16x8 a[4], b[4];
#pragma unroll
        for (int mi = 0; mi < 4; ++mi)
            a[mi] = *reinterpret_cast<const bf16x8*>(
                &As[buf][(wm * 64 + mi * 16 + row_l) * 32 + rchunk]);
#pragma unroll
        for (int ni = 0; ni < 4; ++ni)
            b[ni] = *reinterpret_cast<const bf16x8*>(
                &Bs[buf][(wn * 64 + ni * 16 + row_l) * 32 + rchunk]);

        if (kt + 2 < NT) {
            int st = buf + 2; if (st >= 3) st -= 3;
            stage(st, kt + 2);
        }
        if (kt < NT - 2)       asm volatile("s_waitcnt vmcnt(3)" ::: "memory");
        else if (kt == NT - 2) asm volatile("s_waitcnt vmcnt(0)" ::: "memory");
        __builtin_amdgcn_s_barrier();
        asm volatile("s_waitcnt lgkmcnt(0)" ::: "memory");
        __builtin_amdgcn_sched_barrier(0);
        __builtin_amdgcn_s_setprio(1);
#pragma unroll
        for (int mi = 0; mi < 4; ++mi)
#pragma unroll
            for (int ni = 0; ni < 4; ++ni)
                acc[mi][ni] = __builtin_amdgcn_mfma_f32_16x16x32_bf16(a[mi], b[ni], acc[mi][ni], 0, 0, 0);
        __builtin_amdgcn_s_setprio(0);
        __builtin_amdgcn_s_barrier();
        buf = buf + 1; if (buf >= 3) buf = 0;
    }

#pragma unroll
    for (int ni = 0; ni < 4; ++ni) {
        const int col = n0 + wn * 64 + ni * 16 + row_l;
        const float bsf = bias[col];
#pragma unroll
        for (int mi = 0; mi < 4; ++mi) {
#pragma unroll
            for (int r = 0; r < 4; ++r) {
                const int rowm = m0 + wm * 64 + mi * 16 + grp * 4 + r;
                C[(size_t)rowm * N + col] = f2bf(acc[mi][ni][r] + bsf);
            }
        }
    }
}

// ===== out-proj GEMM: ring-3 128x128 (unchanged) =====
template <bool OUT_BF16>
__launch_bounds__(256, 3)
__global__ void gemm_ring(const u16* __restrict__ A, const u16* __restrict__ W,
                          const float* __restrict__ bias, void* __restrict__ Cv,
                          int M, int N, int K) {
    __shared__ u16 As[3][128 * 32];
    __shared__ u16 Bs[3][128 * 32];

    const int tid   = threadIdx.x;
    const int lane  = tid & 63;
    const int wid   = tid >> 6;
    const int wm    = wid >> 1;
    const int wn    = wid & 1;
    const int row_l = lane & 15;
    const int grp   = lane >> 4;

    const int nwg  = gridDim.x * gridDim.y;
    const int hw   = blockIdx.y * gridDim.x + blockIdx.x;
    const int tile = (hw & 7) * (nwg >> 3) + (hw >> 3);
    const int m0 = (tile / gridDim.x) * 128;
    const int n0 = (tile % gridDim.x) * 128;

    const int srow = tid >> 2;
    const int scol = ((tid & 3) ^ ((tid >> 3) & 3)) * 8;
    const u16* gA = A + (size_t)(m0 + srow) * K + scol;
    const u16* gB = W + (size_t)(n0 + srow) * K + scol;

    f32x4 acc[4][4];
#pragma unroll
    for (int mi = 0; mi < 4; ++mi)
#pragma unroll
        for (int ni = 0; ni < 4; ++ni)
            acc[mi][ni] = (f32x4){0.f, 0.f, 0.f, 0.f};

    auto stage = [&](int buf, int kt) {
#pragma unroll
        for (int i = 0; i < 2; ++i) {
            gload_lds16(gA + (size_t)(i * 64) * K + kt * 32, &As[buf][i * 2048 + wid * 512]);
            gload_lds16(gB + (size_t)(i * 64) * K + kt * 32, &Bs[buf][i * 2048 + wid * 512]);
        }
    };

    const int rchunk = (grp ^ ((row_l >> 1) & 3)) * 8;

    auto compute = [&](int buf) {
        bf16x8 a[4], b[4];
#pragma unroll
        for (int mi = 0; mi < 4; ++mi)
            a[mi] = *reinterpret_cast<const bf16x8*>(
                &As[buf][(wm * 64 + mi * 16 + row_l) * 32 + rchunk]);
#pragma unroll
        for (int ni = 0; ni < 4; ++ni)
            b[ni] = *reinterpret_cast<const bf16x8*>(
                &Bs[buf][(wn * 64 + ni * 16 + row_l) * 32 + rchunk]);
        __builtin_amdgcn_s_setprio(1);
#pragma unroll
        for (int mi = 0; mi < 4; ++mi)
#pragma unroll
            for (int ni = 0; ni < 4; ++ni)
                acc[mi][ni] = __builtin_amdgcn_mfma_f32_16x16x32_bf16(a[mi], b[ni], acc[mi][ni], 0, 0, 0);
        __builtin_amdgcn_s_setprio(0);
    };

    const int NT = K >> 5;
    stage(0, 0);
    stage(1, 1);
    int cur = 0;
    for (int t = 0; t < NT; ++t) {
        if (t == NT - 1) asm volatile("s_waitcnt vmcnt(0)" ::: "memory");
        else             asm volatile("s_waitcnt vmcnt(4)" ::: "memory");
        __builtin_amdgcn_s_barrier();
        if (t + 2 < NT) {
            int st = cur + 2; if (st >= 3) st -= 3;
            stage(st, t + 2);
        }
        compute(cur);
        cur = cur + 1; if (cur >= 3) cur = 0;
    }

#pragma unroll
    for (int ni = 0; ni < 4; ++ni) {
        const int col = n0 + wn * 64 + ni * 16 + row_l;
        const float bsf = bias[col];
#pragma unroll
        for (int mi = 0; mi < 4; ++mi) {
#pragma unroll
            for (int r = 0; r < 4; ++r) {
                const int rowm = m0 + wm * 64 + mi * 16 + grp * 4 + r;
                const float v = acc[mi][ni][r] + bsf;
                if (OUT_BF16)
                    ((u16*)Cv)[(size_t)rowm * N + col] = f2bf(v);
                else
                    ((float*)Cv)[(size_t)rowm * N + col] = v;
            }
        }
    }
}

// ===== banded local attention: Vt conflict-free swizzle + defer-max =====
__launch_bounds__(512, 4)
__global__ void local_attn(const u16* __restrict__ qkv, u16* __restrict__ att) {
    __shared__ __align__(16) u16 Ks[256 * 64];
    __shared__ __align__(16) u16 Vt[64 * 256];
    __shared__ __align__(16) u16 Pl[8][512];

    const int tid   = threadIdx.x;
    const int lane  = tid & 63;
    const int wv    = tid >> 6;
    const int row_l = lane & 15;
    const int grp   = lane >> 4;
    const int qt = blockIdx.x, h = blockIdx.y, b = blockIdx.z;
    const int q0b = qt * 128;
    const int kstart = q0b - 64;
    const size_t base = (size_t)b * L_SEQ * 1536;
    const bool edge = (qt == 0) || (qt == NQT - 1);

    {
        const int r0 = tid >> 3;
        const int c  = tid & 7;
#pragma unroll
        for (int i = 0; i < 4; ++i) {
            const int row  = i * 64 + r0;
            const int keyg = min(max(kstart + row, 0), L_SEQ - 1);
            const int cg   = c ^ (row & 7);
            gload_lds16(qkv + base + (size_t)keyg * 1536 + 512 + h * 64 + cg * 8,
                        &Ks[i * 4096 + wv * 512]);
        }
    }
    {
        // V^T staging: slot = (key>>3) ^ (d&7) ^ ((d>>3)&7) — mixes BOTH d fields
        // so the 8 write-lanes (d = 8m) land in 8 distinct 16B slots (2-way, free),
        // and the b128 read (d = ds*16+row_l) stays 2-way.
#pragma unroll
        for (int i = 0; i < 4; ++i) {
            const int idx  = i * 512 + tid;
            const int row  = idx >> 3;
            const int c8   = idx & 7;
            const int keyg = min(max(kstart + row, 0), L_SEQ - 1);
            const u16x8 vu = *reinterpret_cast<const u16x8*>(
                qkv + base + (size_t)keyg * 1536 + 1024 + h * 64 + c8 * 8);
#pragma unroll
            for (int e = 0; e < 8; ++e) {
                const int d = c8 * 8 + e;
                const int slot = (row >> 3) ^ (d & 7) ^ ((d >> 3) & 7);
                Vt[d * 256 + slot * 8 + (row & 7)] = vu[e];
            }
        }
    }

    const int qrow_g = q0b + wv * 16 + row_l;
    const u16* qp = qkv + base + (size_t)qrow_g * 1536 + h * 64;
    const bf16x8 qf0 = *reinterpret_cast<const bf16x8*>(qp + grp * 8);
    const bf16x8 qf1 = *reinterpret_cast<const bf16x8*>(qp + 32 + grp * 8);

    __syncthreads();

    float m_r = -1e30f, l_r = 0.f;
    f32x4 acc[4];
#pragma unroll
    for (int ds = 0; ds < 4; ++ds) acc[ds] = (f32x4){0.f, 0.f, 0.f, 0.f};
    u16* Pw = Pl[wv];

    auto do_chunk = [&](int c, bool bandLo, bool bandHi, bool half, bool rng) {
        const int kcL = wv * 16 + 32 * c;
        const int kcG = kstart + kcL;
        const int nf = half ? 1 : 2;

        f32x4 s[2];
#pragma unroll
        for (int f = 0; f < 2; ++f) {
            if (f >= nf) break;
            const int rr = kcL + 16 * f + row_l;
            const bf16x8 ka = *reinterpret_cast<const bf16x8*>(
                &Ks[rr * 64 + ((grp ^ (rr & 7)) * 8)]);
            const bf16x8 kb = *reinterpret_cast<const bf16x8*>(
                &Ks[rr * 64 + (((grp + 4) ^ (rr & 7)) * 8)]);
            f32x4 z = (f32x4){0.f, 0.f, 0.f, 0.f};
            z = __builtin_amdgcn_mfma_f32_16x16x32_bf16(ka, qf0, z, 0, 0, 0);
            z = __builtin_amdgcn_mfma_f32_16x16x32_bf16(kb, qf1, z, 0, 0, 0);
            s[f] = z;
        }

        float p[2][4];
        float cmax = -1e30f;
#pragma unroll
        for (int f = 0; f < 2; ++f) {
            if (f >= nf) break;
#pragma unroll
            for (int r = 0; r < 4; ++r) {
                const int k = 16 * f + grp * 4 + r;
                bool ok = true;
                if (bandLo) ok = ok && (k >= row_l);
                if (bandHi) ok = ok && (k <= row_l);
                if (rng) { const int kg = kcG + k; ok = ok && (kg >= 0) && (kg < L_SEQ); }
                const float sv = ok ? s[f][r] * 0.125f : -1e30f;
                p[f][r] = sv;
                cmax = fmaxf(cmax, sv);
            }
        }
        cmax = fmaxf(cmax, __shfl_xor(cmax, 16, 64));
        cmax = fmaxf(cmax, __shfl_xor(cmax, 32, 64));

        // defer-max (T13, THR=8): keep stale max while growth <= 8; P <= e^8.
        const bool need = !__all(cmax <= m_r + 8.f);
        float mu;
        float scl = 1.f;
        if (need) {
            const float mn = fmaxf(m_r, cmax);
            scl = __expf(m_r - mn);
            m_r = mn;
            mu  = mn;
        } else {
            mu = m_r;
        }

        float lsum = 0.f;
#pragma unroll
        for (int f = 0; f < 2; ++f) {
            if (f >= nf) break;
#pragma unroll
            for (int r = 0; r < 4; ++r) {
                const float pv = (p[f][r] <= -1e29f) ? 0.f : __expf(p[f][r] - mu);
                p[f][r] = pv;
                lsum += pv;
            }
        }
        lsum += __shfl_xor(lsum, 16, 64);
        lsum += __shfl_xor(lsum, 32, 64);
        l_r = l_r * scl + lsum;

        if (need) {
            float scl4[4];
#pragma unroll
            for (int r = 0; r < 4; ++r) scl4[r] = __shfl(scl, grp * 4 + r, 64);
#pragma unroll
            for (int ds = 0; ds < 4; ++ds)
#pragma unroll
                for (int r = 0; r < 4; ++r) acc[ds][r] *= scl4[r];
        }

#pragma unroll
        for (int f = 0; f < 2; ++f)
#pragma unroll
            for (int r = 0; r < 4; ++r) {
                const int k = 16 * f + grp * 4 + r;
                const int slot = (k >> 3) ^ ((row_l >> 1) & 3);
                const float pv = (f < nf) ? p[f][r] : 0.f;
                Pw[row_l * 32 + slot * 8 + (k & 7)] = f2bf(pv);
            }
        const bf16x8 pa = *reinterpret_cast<const bf16x8*>(
            &Pw[row_l * 32 + ((grp ^ ((row_l >> 1) & 3)) * 8)]);

        int k0 = kcL + grp * 8;
        if (half) k0 = min(k0, 248);
#pragma unroll
        for (int ds = 0; ds < 4; ++ds) {
            const int d = ds * 16 + row_l;
            const int slot = (k0 >> 3) ^ (d & 7) ^ ((d >> 3) & 7);
            const bf16x8 vf = *reinterpret_cast<const bf16x8*>(
                &Vt[d * 256 + slot * 8]);
            acc[ds] = __builtin_amdgcn_mfma_f32_16x16x32_bf16(pa, vf, acc[ds], 0, 0, 0);
        }
    };

    if (!edge) {
        do_chunk(0, true,  false, false, false);
        do_chunk(1, false, false, false, false);
        do_chunk(2, false, false, false, false);
        do_chunk(3, false, false, false, false);
        do_chunk(4, false, true,  true,  false);
    } else {
        const int kw = kstart + wv * 16;
        if (kw       > -32 && kw       < L_SEQ) do_chunk(0, true,  false, false, true);
        if (kw + 32  > -32 && kw + 32  < L_SEQ) do_chunk(1, false, false, false, true);
        if (kw + 64  > -32 && kw + 64  < L_SEQ) do_chunk(2, false, false, false, true);
        if (kw + 96  > -32 && kw + 96  < L_SEQ) do_chunk(3, false, false, false, true);
        if (kw + 128 > -32 && kw + 128 < L_SEQ) do_chunk(4, false, true,  true,  true);
    }

    const float inv = 1.f / l_r;
    float inv4[4];
#pragma unroll
    for (int r = 0; r < 4; ++r) inv4[r] = __shfl(inv, grp * 4 + r, 64);
    const int qg = q0b + wv * 16 + grp * 4;
#pragma unroll
    for (int r = 0; r < 4; ++r)
#pragma unroll
        for (int ds = 0; ds < 4; ++ds)
            att[(size_t)(b * L_SEQ + qg + r) * 512 + h * 64 + ds * 16 + row_l] =
                f2bf(acc[ds][r] * inv4[r]);
}

extern "C" void kernel_launch(void* const* d_in, const int* in_sizes, int n_in,
                              void* d_out, int out_size, void* d_ws, size_t ws_size,
                              hipStream_t stream) {
    const float* x     = (const float*)d_in[0];
    const float* w_in  = (const float*)d_in[1];
    const float* b_in  = (const float*)d_in[2];
    const float* w_out = (const float*)d_in[3];
    const float* b_out = (const float*)d_in[4];
    float* out = (float*)d_out;

    const int B = 8, L = L_SEQ;
    const int M = B * L;  // 16384

    u16* qkv   = (u16*)d_ws;                      // [M, 1536]  bf16
    u16* att   = qkv   + (size_t)M * 1536;        // [M, 512]   bf16
    u16* x_bf  = att   + (size_t)M * 512;         // [M, 512]   bf16
    u16* wi_bf = x_bf  + (size_t)M * 512;         // [1536, 512] bf16
    u16* wo_bf = wi_bf + (size_t)1536 * 512;      // [512, 512] bf16

    const int nx8  = M * 512 / 8;
    const int nwi8 = 1536 * 512 / 8;
    const int nwo8 = 512 * 512 / 8;
    const int ncvt = nx8 + nwi8 + nwo8;
    cvt_all<<<(ncvt + 255) / 256, 256, 0, stream>>>(x, w_in, w_out, x_bf, wi_bf, wo_bf,
                                                    nx8, nwi8, nwo8);

    gemm_qkv<<<dim3(1536 / 128, M / 256), dim3(512), 0, stream>>>(
        x_bf, wi_bf, b_in, qkv, M, 1536, 512);

    local_attn<<<dim3(NQT, 8, B), dim3(512), 0, stream>>>(qkv, att);

    gemm_ring<false><<<dim3(512 / 128, M / 128), dim3(256), 0, stream>>>(
        att, wo_bf, b_out, out, M, 512, 512);
}